// Round 1
// baseline (161.202 us; speedup 1.0000x reference)
//
#include <hip/hip_runtime.h>

// Soft Voronoi rasterizer: out[y][x][c] = w*s0.rgb + (1-w)*s1.rgb,
// w = sigmoid((d1-d0)*0.25), d_i = |pixel_center - site_i.xy|^2.
// Problem constants are fixed by setup_inputs(): H=W=2048, N_SITES=65536.

#define IMG_W 2048
#define IMG_H 2048
#define N_PIX (IMG_W * IMG_H)
#define INV_SCALE_SQ 0.25f

// 4 pixels per thread: int4 cand loads, 3x float4 output stores.
__global__ __launch_bounds__(256) void voronoi_soft_kernel(
    const float* __restrict__ sites,   // [N_SITES, 5] = x,y,r,g,b
    const int*   __restrict__ cand0,   // [H, W]
    const int*   __restrict__ cand1,   // [H, W]
    float*       __restrict__ out)     // [H, W, 3]
{
    const int tid = blockIdx.x * blockDim.x + threadIdx.x;
    const int pix = tid * 4;
    if (pix >= N_PIX) return;

    const int4 c0 = *reinterpret_cast<const int4*>(cand0 + pix);
    const int4 c1 = *reinterpret_cast<const int4*>(cand1 + pix);
    const int idx0[4] = {c0.x, c0.y, c0.z, c0.w};
    const int idx1[4] = {c1.x, c1.y, c1.z, c1.w};

    float res[12];

    // all 4 pixels share a row (W=2048 divisible by 4)
    const float py = (float)(pix >> 11) + 0.5f;
    const float px_base = (float)(pix & (IMG_W - 1)) + 0.5f;

#pragma unroll
    for (int i = 0; i < 4; ++i) {
        const float px = px_base + (float)i;
        const float* __restrict__ s0 = sites + (size_t)idx0[i] * 5;
        const float* __restrict__ s1 = sites + (size_t)idx1[i] * 5;

        const float s0x = s0[0], s0y = s0[1];
        const float s1x = s1[0], s1y = s1[1];

        const float dx0 = px - s0x, dy0 = py - s0y;
        const float dx1 = px - s1x, dy1 = py - s1y;
        const float d0 = dx0 * dx0 + dy0 * dy0;
        const float d1 = dx1 * dx1 + dy1 * dy1;

        const float t = (d1 - d0) * INV_SCALE_SQ;
        // stable at both tails: expf(+huge)=inf -> w=0; expf(-huge)=0 -> w=1
        const float w = 1.0f / (1.0f + __expf(-t));
        const float wc = 1.0f - w;

        res[i * 3 + 0] = w * s0[2] + wc * s1[2];
        res[i * 3 + 1] = w * s0[3] + wc * s1[3];
        res[i * 3 + 2] = w * s0[4] + wc * s1[4];
    }

    float4* o = reinterpret_cast<float4*>(out + (size_t)pix * 3);
    o[0] = make_float4(res[0], res[1], res[2], res[3]);
    o[1] = make_float4(res[4], res[5], res[6], res[7]);
    o[2] = make_float4(res[8], res[9], res[10], res[11]);
}

extern "C" void kernel_launch(void* const* d_in, const int* in_sizes, int n_in,
                              void* d_out, int out_size, void* d_ws, size_t ws_size,
                              hipStream_t stream) {
    const float* sites = (const float*)d_in[0];   // [65536, 5]
    const int*   cand0 = (const int*)d_in[1];     // [2048, 2048]
    const int*   cand1 = (const int*)d_in[2];     // [2048, 2048]
    // d_in[3]=width, d_in[4]=height: fixed at 2048 by the problem; hardcoded.
    float* out = (float*)d_out;                   // [2048, 2048, 3]

    const int threads = 256;
    const int pixels_per_thread = 4;
    const int total_threads = N_PIX / pixels_per_thread;   // 1,048,576
    const int blocks = total_threads / threads;            // 4096

    voronoi_soft_kernel<<<blocks, threads, 0, stream>>>(sites, cand0, cand1, out);
}

// Round 3
// 138.461 us; speedup vs baseline: 1.1642x; 1.1642x over previous
//
#include <hip/hip_runtime.h>
#include <hip/hip_fp16.h>

// Soft Voronoi rasterizer: out[y][x][c] = w*s0.rgb + (1-w)*s1.rgb,
// w = sigmoid((d1-d0)*0.25), d_i = |pixel_center - site_i.xy|^2.
// Constants fixed by setup_inputs(): H=W=2048, N_SITES=65536.
//
// R2/R3: site gathers were the bottleneck (latency/scattered-request bound:
// VALUBusy 4%, HBM 10%). Repack sites 20B->16B (x,y f32 + rgb f16) in d_ws so
// each gather is ONE aligned global_load_dwordx4 instead of 2-5 split loads.
// R3 fix: __builtin_nontemporal_* requires clang native vectors, not
// HIP_vector_type — use ext_vector_type typedefs.

#define IMG_W 2048
#define IMG_H 2048
#define N_PIX (IMG_W * IMG_H)
#define N_SITES 65536
#define INV_SCALE_SQ 0.25f

typedef int   vint4   __attribute__((ext_vector_type(4)));
typedef float vfloat4 __attribute__((ext_vector_type(4)));

// ---- pre-pass: [N,5] f32 -> [N] {x f32, y f32, (r,g) half2, (b,0) half2} ----
__global__ __launch_bounds__(256) void repack_sites(
    const float* __restrict__ sites, vfloat4* __restrict__ packed)
{
    const int i = blockIdx.x * blockDim.x + threadIdx.x;  // < N_SITES
    const float* s = sites + (size_t)i * 5;
    const __half2 rg = __floats2half2_rn(s[2], s[3]);
    const __half2 b0 = __floats2half2_rn(s[4], 0.0f);
    vfloat4 v;
    v.x = s[0];
    v.y = s[1];
    v.z = __uint_as_float(*reinterpret_cast<const unsigned int*>(&rg));
    v.w = __uint_as_float(*reinterpret_cast<const unsigned int*>(&b0));
    packed[i] = v;
}

__device__ __forceinline__ float3 unpack_rgb(const vfloat4& rec) {
    const unsigned int zu = __float_as_uint(rec.z);
    const unsigned int wu = __float_as_uint(rec.w);
    const __half2 rg = *reinterpret_cast<const __half2*>(&zu);
    const __half2 b0 = *reinterpret_cast<const __half2*>(&wu);
    const float2 rgf = __half22float2(rg);
    return make_float3(rgf.x, rgf.y, __half2float(b0.x));
}

// ---- main: 4 pixels/thread; int4 cand loads, 8x dwordx4 gathers, 3x float4 stores ----
__global__ __launch_bounds__(256) void voronoi_soft_kernel(
    const vfloat4* __restrict__ packed, // [N_SITES] repacked records
    const int*     __restrict__ cand0,  // [H, W]
    const int*     __restrict__ cand1,  // [H, W]
    float*         __restrict__ out)    // [H, W, 3]
{
    const int tid = blockIdx.x * blockDim.x + threadIdx.x;
    const int pix = tid * 4;

    // streamed once: nontemporal so they don't evict the site table from L2
    const vint4 c0 = __builtin_nontemporal_load(reinterpret_cast<const vint4*>(cand0 + pix));
    const vint4 c1 = __builtin_nontemporal_load(reinterpret_cast<const vint4*>(cand1 + pix));
    const int idx0[4] = {c0.x, c0.y, c0.z, c0.w};
    const int idx1[4] = {c1.x, c1.y, c1.z, c1.w};

    // issue all 8 gathers up-front (independent -> overlapped latency)
    vfloat4 r0[4], r1[4];
#pragma unroll
    for (int i = 0; i < 4; ++i) r0[i] = packed[idx0[i]];
#pragma unroll
    for (int i = 0; i < 4; ++i) r1[i] = packed[idx1[i]];

    // all 4 pixels share a row (W divisible by 4)
    const float py = (float)(pix >> 11) + 0.5f;
    const float px_base = (float)(pix & (IMG_W - 1)) + 0.5f;

    float res[12];
#pragma unroll
    for (int i = 0; i < 4; ++i) {
        const float px = px_base + (float)i;
        const float dx0 = px - r0[i].x, dy0 = py - r0[i].y;
        const float dx1 = px - r1[i].x, dy1 = py - r1[i].y;
        const float d0 = dx0 * dx0 + dy0 * dy0;
        const float d1 = dx1 * dx1 + dy1 * dy1;

        const float t = (d1 - d0) * INV_SCALE_SQ;
        // stable at both tails: expf(+huge)=inf -> w=0; expf(-huge)=0 -> w=1
        const float w = 1.0f / (1.0f + __expf(-t));
        const float wc = 1.0f - w;

        const float3 cA = unpack_rgb(r0[i]);
        const float3 cB = unpack_rgb(r1[i]);
        res[i * 3 + 0] = w * cA.x + wc * cB.x;
        res[i * 3 + 1] = w * cA.y + wc * cB.y;
        res[i * 3 + 2] = w * cA.z + wc * cB.z;
    }

    vfloat4* o = reinterpret_cast<vfloat4*>(out + (size_t)pix * 3);
    vfloat4 o0 = {res[0], res[1], res[2], res[3]};
    vfloat4 o1 = {res[4], res[5], res[6], res[7]};
    vfloat4 o2 = {res[8], res[9], res[10], res[11]};
    __builtin_nontemporal_store(o0, o + 0);
    __builtin_nontemporal_store(o1, o + 1);
    __builtin_nontemporal_store(o2, o + 2);
}

// ---- fallback (ws too small): round-1 style direct gather, known-correct ----
__global__ __launch_bounds__(256) void voronoi_soft_fallback(
    const float* __restrict__ sites,
    const int*   __restrict__ cand0,
    const int*   __restrict__ cand1,
    float*       __restrict__ out)
{
    const int tid = blockIdx.x * blockDim.x + threadIdx.x;
    const int pix = tid * 4;
    const int4 c0 = *reinterpret_cast<const int4*>(cand0 + pix);
    const int4 c1 = *reinterpret_cast<const int4*>(cand1 + pix);
    const int idx0[4] = {c0.x, c0.y, c0.z, c0.w};
    const int idx1[4] = {c1.x, c1.y, c1.z, c1.w};
    const float py = (float)(pix >> 11) + 0.5f;
    const float px_base = (float)(pix & (IMG_W - 1)) + 0.5f;
    float res[12];
#pragma unroll
    for (int i = 0; i < 4; ++i) {
        const float px = px_base + (float)i;
        const float* s0 = sites + (size_t)idx0[i] * 5;
        const float* s1 = sites + (size_t)idx1[i] * 5;
        const float dx0 = px - s0[0], dy0 = py - s0[1];
        const float dx1 = px - s1[0], dy1 = py - s1[1];
        const float d0 = dx0 * dx0 + dy0 * dy0;
        const float d1 = dx1 * dx1 + dy1 * dy1;
        const float w = 1.0f / (1.0f + __expf(-(d1 - d0) * INV_SCALE_SQ));
        const float wc = 1.0f - w;
        res[i * 3 + 0] = w * s0[2] + wc * s1[2];
        res[i * 3 + 1] = w * s0[3] + wc * s1[3];
        res[i * 3 + 2] = w * s0[4] + wc * s1[4];
    }
    float4* o = reinterpret_cast<float4*>(out + (size_t)pix * 3);
    o[0] = make_float4(res[0], res[1], res[2], res[3]);
    o[1] = make_float4(res[4], res[5], res[6], res[7]);
    o[2] = make_float4(res[8], res[9], res[10], res[11]);
}

extern "C" void kernel_launch(void* const* d_in, const int* in_sizes, int n_in,
                              void* d_out, int out_size, void* d_ws, size_t ws_size,
                              hipStream_t stream) {
    const float* sites = (const float*)d_in[0];   // [65536, 5]
    const int*   cand0 = (const int*)d_in[1];     // [2048, 2048]
    const int*   cand1 = (const int*)d_in[2];     // [2048, 2048]
    float* out = (float*)d_out;                   // [2048, 2048, 3]

    const int threads = 256;
    const int blocks = N_PIX / (4 * threads);     // 4096

    const size_t packed_bytes = (size_t)N_SITES * sizeof(vfloat4);  // 1 MB
    if (ws_size >= packed_bytes) {
        vfloat4* packed = (vfloat4*)d_ws;
        repack_sites<<<N_SITES / 256, 256, 0, stream>>>(sites, packed);
        voronoi_soft_kernel<<<blocks, threads, 0, stream>>>(packed, cand0, cand1, out);
    } else {
        voronoi_soft_fallback<<<blocks, threads, 0, stream>>>(sites, cand0, cand1, out);
    }
}

// Round 4
// 136.227 us; speedup vs baseline: 1.1833x; 1.0164x over previous
//
#include <hip/hip_runtime.h>
#include <hip/hip_fp16.h>

// Soft Voronoi rasterizer: out[y][x][c] = w*s0.rgb + (1-w)*s1.rgb,
// w = sigmoid((d1-d0)*0.25), d_i = |pixel_center - site_i.xy|^2.
// Constants fixed by setup_inputs(): H=W=2048, N_SITES=65536.
//
// R2/R3: site gathers were the bottleneck (latency/scattered-request bound).
// Repacked sites 20B->16B (x,y f32 + rgb f16) in d_ws: one dwordx4 per gather.
// 86 -> 56 us.
// R4: NT *stores* caused 78MB vs 48MB write amplification (partial 64B lines
// bypass L2 write-combining). Revert to normal cached stores; keep NT only on
// the streaming cand loads (protects site table L2 residency, FETCH was fine).

#define IMG_W 2048
#define IMG_H 2048
#define N_PIX (IMG_W * IMG_H)
#define N_SITES 65536
#define INV_SCALE_SQ 0.25f

typedef int   vint4   __attribute__((ext_vector_type(4)));
typedef float vfloat4 __attribute__((ext_vector_type(4)));

// ---- pre-pass: [N,5] f32 -> [N] {x f32, y f32, (r,g) half2, (b,0) half2} ----
__global__ __launch_bounds__(256) void repack_sites(
    const float* __restrict__ sites, vfloat4* __restrict__ packed)
{
    const int i = blockIdx.x * blockDim.x + threadIdx.x;  // < N_SITES
    const float* s = sites + (size_t)i * 5;
    const __half2 rg = __floats2half2_rn(s[2], s[3]);
    const __half2 b0 = __floats2half2_rn(s[4], 0.0f);
    vfloat4 v;
    v.x = s[0];
    v.y = s[1];
    v.z = __uint_as_float(*reinterpret_cast<const unsigned int*>(&rg));
    v.w = __uint_as_float(*reinterpret_cast<const unsigned int*>(&b0));
    packed[i] = v;
}

__device__ __forceinline__ float3 unpack_rgb(const vfloat4& rec) {
    const unsigned int zu = __float_as_uint(rec.z);
    const unsigned int wu = __float_as_uint(rec.w);
    const __half2 rg = *reinterpret_cast<const __half2*>(&zu);
    const __half2 b0 = *reinterpret_cast<const __half2*>(&wu);
    const float2 rgf = __half22float2(rg);
    return make_float3(rgf.x, rgf.y, __half2float(b0.x));
}

// ---- main: 4 pixels/thread; NT int4 cand loads, 8x dwordx4 gathers,
//      3x cached float4 stores (L2 write-back merges the 48B-stride pattern) ----
__global__ __launch_bounds__(256) void voronoi_soft_kernel(
    const vfloat4* __restrict__ packed, // [N_SITES] repacked records
    const int*     __restrict__ cand0,  // [H, W]
    const int*     __restrict__ cand1,  // [H, W]
    float*         __restrict__ out)    // [H, W, 3]
{
    const int tid = blockIdx.x * blockDim.x + threadIdx.x;
    const int pix = tid * 4;

    // streamed once: nontemporal so they don't evict the site table from L2
    const vint4 c0 = __builtin_nontemporal_load(reinterpret_cast<const vint4*>(cand0 + pix));
    const vint4 c1 = __builtin_nontemporal_load(reinterpret_cast<const vint4*>(cand1 + pix));
    const int idx0[4] = {c0.x, c0.y, c0.z, c0.w};
    const int idx1[4] = {c1.x, c1.y, c1.z, c1.w};

    // issue all 8 gathers up-front (independent -> overlapped latency)
    vfloat4 r0[4], r1[4];
#pragma unroll
    for (int i = 0; i < 4; ++i) r0[i] = packed[idx0[i]];
#pragma unroll
    for (int i = 0; i < 4; ++i) r1[i] = packed[idx1[i]];

    // all 4 pixels share a row (W divisible by 4)
    const float py = (float)(pix >> 11) + 0.5f;
    const float px_base = (float)(pix & (IMG_W - 1)) + 0.5f;

    float res[12];
#pragma unroll
    for (int i = 0; i < 4; ++i) {
        const float px = px_base + (float)i;
        const float dx0 = px - r0[i].x, dy0 = py - r0[i].y;
        const float dx1 = px - r1[i].x, dy1 = py - r1[i].y;
        const float d0 = dx0 * dx0 + dy0 * dy0;
        const float d1 = dx1 * dx1 + dy1 * dy1;

        const float t = (d1 - d0) * INV_SCALE_SQ;
        // stable at both tails: expf(+huge)=inf -> w=0; expf(-huge)=0 -> w=1
        const float w = 1.0f / (1.0f + __expf(-t));
        const float wc = 1.0f - w;

        const float3 cA = unpack_rgb(r0[i]);
        const float3 cB = unpack_rgb(r1[i]);
        res[i * 3 + 0] = w * cA.x + wc * cB.x;
        res[i * 3 + 1] = w * cA.y + wc * cB.y;
        res[i * 3 + 2] = w * cA.z + wc * cB.z;
    }

    // normal cached stores: L2 write-back merges the partial-line pattern
    vfloat4* o = reinterpret_cast<vfloat4*>(out + (size_t)pix * 3);
    vfloat4 o0 = {res[0], res[1], res[2], res[3]};
    vfloat4 o1 = {res[4], res[5], res[6], res[7]};
    vfloat4 o2 = {res[8], res[9], res[10], res[11]};
    o[0] = o0;
    o[1] = o1;
    o[2] = o2;
}

// ---- fallback (ws too small): round-1 style direct gather, known-correct ----
__global__ __launch_bounds__(256) void voronoi_soft_fallback(
    const float* __restrict__ sites,
    const int*   __restrict__ cand0,
    const int*   __restrict__ cand1,
    float*       __restrict__ out)
{
    const int tid = blockIdx.x * blockDim.x + threadIdx.x;
    const int pix = tid * 4;
    const int4 c0 = *reinterpret_cast<const int4*>(cand0 + pix);
    const int4 c1 = *reinterpret_cast<const int4*>(cand1 + pix);
    const int idx0[4] = {c0.x, c0.y, c0.z, c0.w};
    const int idx1[4] = {c1.x, c1.y, c1.z, c1.w};
    const float py = (float)(pix >> 11) + 0.5f;
    const float px_base = (float)(pix & (IMG_W - 1)) + 0.5f;
    float res[12];
#pragma unroll
    for (int i = 0; i < 4; ++i) {
        const float px = px_base + (float)i;
        const float* s0 = sites + (size_t)idx0[i] * 5;
        const float* s1 = sites + (size_t)idx1[i] * 5;
        const float dx0 = px - s0[0], dy0 = py - s0[1];
        const float dx1 = px - s1[0], dy1 = py - s1[1];
        const float d0 = dx0 * dx0 + dy0 * dy0;
        const float d1 = dx1 * dx1 + dy1 * dy1;
        const float w = 1.0f / (1.0f + __expf(-(d1 - d0) * INV_SCALE_SQ));
        const float wc = 1.0f - w;
        res[i * 3 + 0] = w * s0[2] + wc * s1[2];
        res[i * 3 + 1] = w * s0[3] + wc * s1[3];
        res[i * 3 + 2] = w * s0[4] + wc * s1[4];
    }
    float4* o = reinterpret_cast<float4*>(out + (size_t)pix * 3);
    o[0] = make_float4(res[0], res[1], res[2], res[3]);
    o[1] = make_float4(res[4], res[5], res[6], res[7]);
    o[2] = make_float4(res[8], res[9], res[10], res[11]);
}

extern "C" void kernel_launch(void* const* d_in, const int* in_sizes, int n_in,
                              void* d_out, int out_size, void* d_ws, size_t ws_size,
                              hipStream_t stream) {
    const float* sites = (const float*)d_in[0];   // [65536, 5]
    const int*   cand0 = (const int*)d_in[1];     // [2048, 2048]
    const int*   cand1 = (const int*)d_in[2];     // [2048, 2048]
    float* out = (float*)d_out;                   // [2048, 2048, 3]

    const int threads = 256;
    const int blocks = N_PIX / (4 * threads);     // 4096

    const size_t packed_bytes = (size_t)N_SITES * sizeof(vfloat4);  // 1 MB
    if (ws_size >= packed_bytes) {
        vfloat4* packed = (vfloat4*)d_ws;
        repack_sites<<<N_SITES / 256, 256, 0, stream>>>(sites, packed);
        voronoi_soft_kernel<<<blocks, threads, 0, stream>>>(packed, cand0, cand1, out);
    } else {
        voronoi_soft_fallback<<<blocks, threads, 0, stream>>>(sites, cand0, cand1, out);
    }
}

// Round 6
// 131.682 us; speedup vs baseline: 1.2242x; 1.0345x over previous
//
#include <hip/hip_runtime.h>
#include <hip/hip_fp16.h>

// Soft Voronoi rasterizer: out[y][x][c] = w*s0.rgb + (1-w)*s1.rgb,
// w = sigmoid((d1-d0)*0.25), d_i = |pixel_center - site_i.xy|^2.
// Constants fixed by setup_inputs(): H=W=2048, N_SITES=65536.
//
// R2/R3: repacked sites 20B->16B (x,y f32 + rgb f16): one dwordx4 per gather
// (86 -> 56 us). R4: NT stores caused 78MB write amplification; reverted
// (write 49MB, dur flat -> not write-bound). R5: sc0 L1-bypass gathers, but
// asm outputs lacked early-clobber -> output regs aliased later loads'
// address regs -> wild address -> GPU fault. R6: same experiment, "=&v".

#define IMG_W 2048
#define IMG_H 2048
#define N_PIX (IMG_W * IMG_H)
#define N_SITES 65536
#define INV_SCALE_SQ 0.25f

typedef int   vint4   __attribute__((ext_vector_type(4)));
typedef float vfloat4 __attribute__((ext_vector_type(4)));

// ---- pre-pass: [N,5] f32 -> [N] {x f32, y f32, (r,g) half2, (b,0) half2} ----
__global__ __launch_bounds__(256) void repack_sites(
    const float* __restrict__ sites, vfloat4* __restrict__ packed)
{
    const int i = blockIdx.x * blockDim.x + threadIdx.x;  // < N_SITES
    const float* s = sites + (size_t)i * 5;
    const __half2 rg = __floats2half2_rn(s[2], s[3]);
    const __half2 b0 = __floats2half2_rn(s[4], 0.0f);
    vfloat4 v;
    v.x = s[0];
    v.y = s[1];
    v.z = __uint_as_float(*reinterpret_cast<const unsigned int*>(&rg));
    v.w = __uint_as_float(*reinterpret_cast<const unsigned int*>(&b0));
    packed[i] = v;
}

__device__ __forceinline__ float3 unpack_rgb(const vfloat4& rec) {
    const unsigned int zu = __float_as_uint(rec.z);
    const unsigned int wu = __float_as_uint(rec.w);
    const __half2 rg = *reinterpret_cast<const __half2*>(&zu);
    const __half2 b0 = *reinterpret_cast<const __half2*>(&wu);
    const float2 rgf = __half22float2(rg);
    return make_float3(rgf.x, rgf.y, __half2float(b0.x));
}

// ---- main: 4 pixels/thread; NT int4 cand loads, 8x sc0 dwordx4 gathers
//      (L1-bypass -> L2 direct), 3x cached float4 stores ----
__global__ __launch_bounds__(256) void voronoi_soft_kernel(
    const vfloat4* __restrict__ packed, // [N_SITES] repacked records
    const int*     __restrict__ cand0,  // [H, W]
    const int*     __restrict__ cand1,  // [H, W]
    float*         __restrict__ out)    // [H, W, 3]
{
    const int tid = blockIdx.x * blockDim.x + threadIdx.x;
    const int pix = tid * 4;

    // streamed once: nontemporal so they don't evict the site table from L2
    const vint4 c0 = __builtin_nontemporal_load(reinterpret_cast<const vint4*>(cand0 + pix));
    const vint4 c1 = __builtin_nontemporal_load(reinterpret_cast<const vint4*>(cand1 + pix));

    const vfloat4* p00 = packed + c0.x;
    const vfloat4* p01 = packed + c0.y;
    const vfloat4* p02 = packed + c0.z;
    const vfloat4* p03 = packed + c0.w;
    const vfloat4* p10 = packed + c1.x;
    const vfloat4* p11 = packed + c1.y;
    const vfloat4* p12 = packed + c1.z;
    const vfloat4* p13 = packed + c1.w;

    // 8 L1-bypassing gathers issued back-to-back, one drain. sc0 = agent
    // coherent: skips the (thrashing, non-coherent) 32KiB L1, hits L2 where
    // the 1MB table is resident. "=&v" early-clobber: outputs must not alias
    // the address register pairs of later loads in the block (R5 fault).
    vfloat4 r0[4], r1[4];
    asm volatile(
        "global_load_dwordx4 %0, %8, off sc0\n\t"
        "global_load_dwordx4 %1, %9, off sc0\n\t"
        "global_load_dwordx4 %2, %10, off sc0\n\t"
        "global_load_dwordx4 %3, %11, off sc0\n\t"
        "global_load_dwordx4 %4, %12, off sc0\n\t"
        "global_load_dwordx4 %5, %13, off sc0\n\t"
        "global_load_dwordx4 %6, %14, off sc0\n\t"
        "global_load_dwordx4 %7, %15, off sc0\n\t"
        "s_waitcnt vmcnt(0)"
        : "=&v"(r0[0]), "=&v"(r0[1]), "=&v"(r0[2]), "=&v"(r0[3]),
          "=&v"(r1[0]), "=&v"(r1[1]), "=&v"(r1[2]), "=&v"(r1[3])
        : "v"(p00), "v"(p01), "v"(p02), "v"(p03),
          "v"(p10), "v"(p11), "v"(p12), "v"(p13)
        : "memory");

    // all 4 pixels share a row (W divisible by 4)
    const float py = (float)(pix >> 11) + 0.5f;
    const float px_base = (float)(pix & (IMG_W - 1)) + 0.5f;

    float res[12];
#pragma unroll
    for (int i = 0; i < 4; ++i) {
        const float px = px_base + (float)i;
        const float dx0 = px - r0[i].x, dy0 = py - r0[i].y;
        const float dx1 = px - r1[i].x, dy1 = py - r1[i].y;
        const float d0 = dx0 * dx0 + dy0 * dy0;
        const float d1 = dx1 * dx1 + dy1 * dy1;

        const float t = (d1 - d0) * INV_SCALE_SQ;
        // stable at both tails: expf(+huge)=inf -> w=0; expf(-huge)=0 -> w=1
        const float w = 1.0f / (1.0f + __expf(-t));
        const float wc = 1.0f - w;

        const float3 cA = unpack_rgb(r0[i]);
        const float3 cB = unpack_rgb(r1[i]);
        res[i * 3 + 0] = w * cA.x + wc * cB.x;
        res[i * 3 + 1] = w * cA.y + wc * cB.y;
        res[i * 3 + 2] = w * cA.z + wc * cB.z;
    }

    // normal cached stores: L2 write-back merges the partial-line pattern
    vfloat4* o = reinterpret_cast<vfloat4*>(out + (size_t)pix * 3);
    vfloat4 o0 = {res[0], res[1], res[2], res[3]};
    vfloat4 o1 = {res[4], res[5], res[6], res[7]};
    vfloat4 o2 = {res[8], res[9], res[10], res[11]};
    o[0] = o0;
    o[1] = o1;
    o[2] = o2;
}

// ---- fallback (ws too small): round-1 style direct gather, known-correct ----
__global__ __launch_bounds__(256) void voronoi_soft_fallback(
    const float* __restrict__ sites,
    const int*   __restrict__ cand0,
    const int*   __restrict__ cand1,
    float*       __restrict__ out)
{
    const int tid = blockIdx.x * blockDim.x + threadIdx.x;
    const int pix = tid * 4;
    const int4 c0 = *reinterpret_cast<const int4*>(cand0 + pix);
    const int4 c1 = *reinterpret_cast<const int4*>(cand1 + pix);
    const int idx0[4] = {c0.x, c0.y, c0.z, c0.w};
    const int idx1[4] = {c1.x, c1.y, c1.z, c1.w};
    const float py = (float)(pix >> 11) + 0.5f;
    const float px_base = (float)(pix & (IMG_W - 1)) + 0.5f;
    float res[12];
#pragma unroll
    for (int i = 0; i < 4; ++i) {
        const float px = px_base + (float)i;
        const float* s0 = sites + (size_t)idx0[i] * 5;
        const float* s1 = sites + (size_t)idx1[i] * 5;
        const float dx0 = px - s0[0], dy0 = py - s0[1];
        const float dx1 = px - s1[0], dy1 = py - s1[1];
        const float d0 = dx0 * dx0 + dy0 * dy0;
        const float d1 = dx1 * dx1 + dy1 * dy1;
        const float w = 1.0f / (1.0f + __expf(-(d1 - d0) * INV_SCALE_SQ));
        const float wc = 1.0f - w;
        res[i * 3 + 0] = w * s0[2] + wc * s1[2];
        res[i * 3 + 1] = w * s0[3] + wc * s1[3];
        res[i * 3 + 2] = w * s0[4] + wc * s1[4];
    }
    float4* o = reinterpret_cast<float4*>(out + (size_t)pix * 3);
    o[0] = make_float4(res[0], res[1], res[2], res[3]);
    o[1] = make_float4(res[4], res[5], res[6], res[7]);
    o[2] = make_float4(res[8], res[9], res[10], res[11]);
}

extern "C" void kernel_launch(void* const* d_in, const int* in_sizes, int n_in,
                              void* d_out, int out_size, void* d_ws, size_t ws_size,
                              hipStream_t stream) {
    const float* sites = (const float*)d_in[0];   // [65536, 5]
    const int*   cand0 = (const int*)d_in[1];     // [2048, 2048]
    const int*   cand1 = (const int*)d_in[2];     // [2048, 2048]
    float* out = (float*)d_out;                   // [2048, 2048, 3]

    const int threads = 256;
    const int blocks = N_PIX / (4 * threads);     // 4096

    const size_t packed_bytes = (size_t)N_SITES * sizeof(vfloat4);  // 1 MB
    if (ws_size >= packed_bytes) {
        vfloat4* packed = (vfloat4*)d_ws;
        repack_sites<<<N_SITES / 256, 256, 0, stream>>>(sites, packed);
        voronoi_soft_kernel<<<blocks, threads, 0, stream>>>(packed, cand0, cand1, out);
    } else {
        voronoi_soft_fallback<<<blocks, threads, 0, stream>>>(sites, cand0, cand1, out);
    }
}